// Round 3
// baseline (155.005 us; speedup 1.0000x reference)
//
#include <hip/hip_runtime.h>

#define NB 2
#define NN 64
#define NE 128
#define NH 8
#define ND 16
#define NC 64          // E/2
#define NROWS (NB*NN*NN)  // 8192

// ---------------- k1: LayerNorm + 4 projections (q*scale, k_e, v_e, gate) ----------------
__global__ __launch_bounds__(256) void tri_k1(
    const float* __restrict__ pair_emb,
    const float* __restrict__ ln_g, const float* __restrict__ ln_b,
    const float* __restrict__ Wq, const float* __restrict__ bq,
    const float* __restrict__ Wke, const float* __restrict__ bke,
    const float* __restrict__ Wv, const float* __restrict__ bv,
    const float* __restrict__ Wg, const float* __restrict__ bg,
    float* __restrict__ qo, float* __restrict__ keo,
    float* __restrict__ veo, float* __restrict__ gateo)
{
    __shared__ float pe_s[16][NE];
    const int tid = threadIdx.x;
    const int wave = tid >> 6, lane = tid & 63;
    const int row0 = blockIdx.x * 16;

    for (int r = wave * 4; r < wave * 4 + 4; ++r) {
        const int row = row0 + r;
        float2 v = *reinterpret_cast<const float2*>(&pair_emb[(size_t)row * NE + lane * 2]);
        float s = v.x + v.y, s2 = v.x * v.x + v.y * v.y;
        #pragma unroll
        for (int m = 1; m < 64; m <<= 1) { s += __shfl_xor(s, m); s2 += __shfl_xor(s2, m); }
        const float mean = s * (1.0f / NE);
        const float var = fmaxf(s2 * (1.0f / NE) - mean * mean, 0.0f);
        const float inv = rsqrtf(var + 1e-5f);
        pe_s[r][lane * 2]     = (v.x - mean) * inv * ln_g[lane * 2]     + ln_b[lane * 2];
        pe_s[r][lane * 2 + 1] = (v.y - mean) * inv * ln_g[lane * 2 + 1] + ln_b[lane * 2 + 1];
    }
    __syncthreads();

    const int o = tid & 127;
    const int half = tid >> 7;
    float aq[8] = {0,0,0,0,0,0,0,0}, ak[8] = {0,0,0,0,0,0,0,0};
    float av[8] = {0,0,0,0,0,0,0,0}, ag[8] = {0,0,0,0,0,0,0,0};
    for (int c = 0; c < NE; ++c) {
        const float wq = Wq[c * NE + o];
        const float wk = Wke[c * NE + o];
        const float wv = Wv[c * NE + o];
        const float wg = Wg[c * NE + o];
        #pragma unroll
        for (int r = 0; r < 8; ++r) {
            const float p = pe_s[half * 8 + r][c];
            aq[r] += p * wq; ak[r] += p * wk; av[r] += p * wv; ag[r] += p * wg;
        }
    }
    #pragma unroll
    for (int r = 0; r < 8; ++r) {
        const size_t row = (size_t)row0 + half * 8 + r;
        qo[row * NE + o]    = (aq[r] + bq[o]) * 0.25f;
        keo[row * NE + o]   = ak[r] + bke[o];
        veo[row * NE + o]   = av[r] + bv[o];
        gateo[row * NE + o] = 1.0f / (1.0f + __expf(-(ag[r] + bg[o])));
    }
}

// ---------------- k1b: per (b,i, x-half): S0[x,h,j] = q·k_e + q·bka + bias ; qw = Wka^T q ----
__global__ __launch_bounds__(256) void tri_k1b(
    const float* __restrict__ qv, const float* __restrict__ kev,
    const float* __restrict__ mask,
    const float* __restrict__ Wka, const float* __restrict__ bka,
    float* __restrict__ S0g, float* __restrict__ qwg)
{
    __shared__ float qt[32][129];
    __shared__ float ket[NN][NE];
    __shared__ float wka_s[NC][NE];
    __shared__ float msk[NN][33];     // [j][x-local]
    __shared__ float bka_s[NE];

    const int tid = threadIdx.x;
    const int blk = blockIdx.x >> 1;  // (b,i), 0..127
    const int xh  = blockIdx.x & 1;
    const int b = blk >> 6;
    const size_t base = (size_t)blk * NN;
    const int xloc0 = xh * 32;

    #pragma unroll
    for (int k = 0; k < 8; ++k) {
        const int v = tid + k * 256;
        const int r = v >> 5, c4 = (v & 31) * 4;
        *reinterpret_cast<float4*>(&ket[r][c4]) =
            *reinterpret_cast<const float4*>(&kev[(base + r) * NE + c4]);
        *reinterpret_cast<float4*>(&wka_s[r][c4]) =
            *reinterpret_cast<const float4*>(&Wka[(size_t)r * NE + c4]);
    }
    #pragma unroll
    for (int k = 0; k < 4; ++k) {
        const int v = tid + k * 256;
        const int r = v >> 5, c4 = (v & 31) * 4;
        float4 tq = *reinterpret_cast<const float4*>(&qv[(base + xloc0 + r) * NE + c4]);
        qt[r][c4] = tq.x; qt[r][c4+1] = tq.y; qt[r][c4+2] = tq.z; qt[r][c4+3] = tq.w;
    }
    #pragma unroll
    for (int k = 0; k < 8; ++k) {
        const int v = tid + k * 256;
        const int j = v >> 5, xl = v & 31;
        msk[j][xl] = mask[(size_t)b * 4096 + j * 64 + xloc0 + xl];
    }
    if (tid < 32) {
        *reinterpret_cast<float4*>(&bka_s[tid * 4]) =
            *reinterpret_cast<const float4*>(&bka[tid * 4]);
    }
    __syncthreads();

    const int xl = tid & 31, h = tid >> 5;
    const int x = xloc0 + xl;
    float qA[16];
    #pragma unroll
    for (int d = 0; d < 16; ++d) qA[d] = qt[xl][h * 16 + d];
    float qbA = 0.0f;
    #pragma unroll
    for (int d = 0; d < 16; ++d) qbA += qA[d] * bka_s[h * 16 + d];

    for (int j4 = 0; j4 < 16; ++j4) {
        float sA[4];
        #pragma unroll
        for (int jj = 0; jj < 4; ++jj) {
            const int j = j4 * 4 + jj;
            float aA = qbA + 1e-9f * (1.0f - msk[j][xl]);
            const float4* kj = reinterpret_cast<const float4*>(&ket[j][h * 16]);
            #pragma unroll
            for (int d4 = 0; d4 < 4; ++d4) {
                const float4 kv = kj[d4];
                aA += qA[d4*4+0]*kv.x + qA[d4*4+1]*kv.y + qA[d4*4+2]*kv.z + qA[d4*4+3]*kv.w;
            }
            sA[jj] = aA;
        }
        *reinterpret_cast<float4*>(&S0g[(base + x) * 512 + h * 64 + j4 * 4]) =
            make_float4(sA[0], sA[1], sA[2], sA[3]);
    }
    for (int c4 = 0; c4 < 16; ++c4) {
        float sA[4];
        #pragma unroll
        for (int cc = 0; cc < 4; ++cc) {
            const int c = c4 * 4 + cc;
            float aA = 0.0f;
            const float4* wj = reinterpret_cast<const float4*>(&wka_s[c][h * 16]);
            #pragma unroll
            for (int d4 = 0; d4 < 4; ++d4) {
                const float4 wv = wj[d4];
                aA += qA[d4*4+0]*wv.x + qA[d4*4+1]*wv.y + qA[d4*4+2]*wv.z + qA[d4*4+3]*wv.w;
            }
            sA[cc] = aA;
        }
        *reinterpret_cast<float4*>(&qwg[(base + x) * 512 + h * 64 + c4 * 4]) =
            make_float4(sA[0], sA[1], sA[2], sA[3]);
    }
}

// ---------------- k2: block per (b,i,g): v_e staged once, 8 tri tiles pipelined ----------------
__global__ __launch_bounds__(256) void tri_k2(
    const float* __restrict__ tri, const float* __restrict__ S0g,
    const float* __restrict__ qwg, const float* __restrict__ vev,
    float* __restrict__ tg, float* __restrict__ preg)
{
    __shared__ float vev_s[64][128];       // [j][e]
    __shared__ float tri_s[2][64][68];     // [buf][j][c], stride 68 -> conflict-free b128 rows
    __shared__ float qw_s[2][8][68];
    __shared__ float sc_s[2][8][72];
    __shared__ float pre_p[2][128];

    const int tid = threadIdx.x;
    const int bid = blockIdx.x;
    // XCD swizzle: all 8 g-blocks of one (b,i) on same XCD (assumes round-robin dispatch)
    const int xcd = bid & 7, slot = bid >> 3;
    const int g = slot >> 4;                   // 0..7
    const int bi = xcd * 16 + (slot & 15);     // 0..127
    const size_t base_bi = (size_t)bi * NN;
    const int x0 = g * 8;

    // stage v_e [64][128] (32 KB) once
    #pragma unroll
    for (int k = 0; k < 8; ++k) {
        const int v = tid + k * 256;
        const int j = v >> 5, e4 = (v & 31) * 4;
        *reinterpret_cast<float4*>(&vev_s[j][e4]) =
            *reinterpret_cast<const float4*>(&vev[(base_bi + j) * NE + e4]);
    }

    // prefetch tile 0 into regs
    float4 pf0, pf1, pf2, pf3;
    float pqw0, pqw1, ps0, ps1;
    {
        const float4* tp = reinterpret_cast<const float4*>(tri) + (base_bi + x0) * 1024;
        pf0 = tp[tid]; pf1 = tp[tid + 256]; pf2 = tp[tid + 512]; pf3 = tp[tid + 768];
        const size_t q0 = (base_bi + x0) * 512;
        pqw0 = qwg[q0 + tid]; pqw1 = qwg[q0 + tid + 256];
        ps0  = S0g[q0 + tid]; ps1  = S0g[q0 + tid + 256];
    }

    int cur = 0;
    for (int t = 0; t < 8; ++t) {
        // commit prefetched tile into LDS[cur]
        {
            const int jw = tid >> 4, c4w = (tid & 15) * 4;
            *reinterpret_cast<float4*>(&tri_s[cur][jw][c4w])      = pf0;
            *reinterpret_cast<float4*>(&tri_s[cur][jw + 16][c4w]) = pf1;
            *reinterpret_cast<float4*>(&tri_s[cur][jw + 32][c4w]) = pf2;
            *reinterpret_cast<float4*>(&tri_s[cur][jw + 48][c4w]) = pf3;
            qw_s[cur][tid >> 6][tid & 63]       = pqw0;
            qw_s[cur][(tid >> 6) + 4][tid & 63] = pqw1;
            sc_s[cur][tid >> 6][tid & 63]       = ps0;
            sc_s[cur][(tid >> 6) + 4][tid & 63] = ps1;
        }
        __syncthreads();

        // prefetch next tile (hides HBM latency under compute below)
        if (t < 7) {
            const int x = x0 + t + 1;
            const float4* tp = reinterpret_cast<const float4*>(tri) + (base_bi + x) * 1024;
            pf0 = tp[tid]; pf1 = tp[tid + 256]; pf2 = tp[tid + 512]; pf3 = tp[tid + 768];
            const size_t q0 = (base_bi + x) * 512;
            pqw0 = qwg[q0 + tid]; pqw1 = qwg[q0 + tid + 256];
            ps0  = S0g[q0 + tid]; ps1  = S0g[q0 + tid + 256];
        }

        // scores[h][j] = S0 + tri[j]·qw[h]   (each thread owns (h,j0),(h,j0+32))
        {
            const int h = tid & 7, j0 = tid >> 3;
            float a0 = sc_s[cur][h][j0], a1 = sc_s[cur][h][j0 + 32];
            #pragma unroll 4
            for (int c4 = 0; c4 < 64; c4 += 4) {
                const float4 w  = *reinterpret_cast<const float4*>(&qw_s[cur][h][c4]);
                const float4 t0 = *reinterpret_cast<const float4*>(&tri_s[cur][j0][c4]);
                const float4 t1 = *reinterpret_cast<const float4*>(&tri_s[cur][j0 + 32][c4]);
                a0 += t0.x * w.x + t0.y * w.y + t0.z * w.z + t0.w * w.w;
                a1 += t1.x * w.x + t1.y * w.y + t1.z * w.z + t1.w * w.w;
            }
            sc_s[cur][h][j0] = a0;
            sc_s[cur][h][j0 + 32] = a1;
        }
        __syncthreads();

        // softmax over j per h
        {
            const int hh = tid >> 5, l = tid & 31;
            const float v0 = sc_s[cur][hh][l], v1 = sc_s[cur][hh][l + 32];
            float m = fmaxf(v0, v1);
            #pragma unroll
            for (int msk = 1; msk < 32; msk <<= 1) m = fmaxf(m, __shfl_xor(m, msk));
            const float e0 = __expf(v0 - m), e1 = __expf(v1 - m);
            float s = e0 + e1;
            #pragma unroll
            for (int msk = 1; msk < 32; msk <<= 1) s += __shfl_xor(s, msk);
            const float inv = 1.0f / s;
            sc_s[cur][hh][l] = e0 * inv;
            sc_s[cur][hh][l + 32] = e1 * inv;
        }
        __syncthreads();

        const size_t bix = base_bi + x0 + t;
        // t[h][c] = sum_j attn[h][j] tri[j][c]
        {
            const int c = tid & 63, h2 = tid >> 6;
            float acc0 = 0.0f, acc1 = 0.0f;
            #pragma unroll 8
            for (int j = 0; j < 64; ++j) {
                const float tv = tri_s[cur][j][c];
                acc0 += sc_s[cur][h2][j] * tv;
                acc1 += sc_s[cur][h2 + 4][j] * tv;
            }
            tg[bix * 512 + tid]       = acc0;
            tg[bix * 512 + tid + 256] = acc1;
        }
        // pre[e] = sum_j attn[h(e)][j] * v_e[j][e]  (j split over 2 halves)
        {
            const int e = tid & 127, g2 = tid >> 7;
            const int hh = e >> 4;
            float acc = 0.0f;
            #pragma unroll 8
            for (int j = g2 * 32; j < g2 * 32 + 32; ++j)
                acc += sc_s[cur][hh][j] * vev_s[j][e];
            pre_p[g2][e] = acc;
        }
        __syncthreads();
        if (tid < 128)
            preg[bix * NE + tid] = pre_p[0][tid] + pre_p[1][tid];
        cur ^= 1;
        // no trailing barrier needed: next commit targets the other buffer, and
        // the pre_p barrier above guarantees compute t-1 is globally finished.
    }
}

// ---------------- k3: out = ((pre + bva + t@Wva) @ Wo + bo) * gate ----------------
__global__ __launch_bounds__(256) void tri_k3(
    const float* __restrict__ tg, const float* __restrict__ preg,
    const float* __restrict__ gatev,
    const float* __restrict__ Wva, const float* __restrict__ bva,
    const float* __restrict__ Wo, const float* __restrict__ bo,
    float* __restrict__ out)
{
    __shared__ float wva_s[64][160];   // gapped: col(e) = e + 4*(e/16)
    __shared__ float wo_s[128][128];
    __shared__ float o_s[32][132];

    const int tid = threadIdx.x;
    const int row0 = blockIdx.x * 32;

    #pragma unroll
    for (int k = 0; k < 8; ++k) {
        const int v = tid + k * 256;
        const int c = v >> 5, e4 = (v & 31) * 4;
        const int col = e4 + ((e4 >> 4) << 2);
        *reinterpret_cast<float4*>(&wva_s[c][col]) =
            *reinterpret_cast<const float4*>(&Wva[(size_t)c * NE + e4]);
    }
    #pragma unroll
    for (int k = 0; k < 16; ++k) {
        const int v = tid + k * 256;
        const int kk = v >> 5, e4 = (v & 31) * 4;
        *reinterpret_cast<float4*>(&wo_s[kk][e4]) =
            *reinterpret_cast<const float4*>(&Wo[(size_t)kk * NE + e4]);
    }
    __syncthreads();

    {
        const int r = tid >> 3, h = tid & 7;
        const size_t row = (size_t)row0 + r;
        float4 acc[4];
        #pragma unroll
        for (int d4 = 0; d4 < 4; ++d4) {
            const float4 p  = *reinterpret_cast<const float4*>(&preg[row * NE + h * 16 + d4 * 4]);
            const float4 bv = *reinterpret_cast<const float4*>(&bva[h * 16 + d4 * 4]);
            acc[d4].x = p.x + bv.x; acc[d4].y = p.y + bv.y;
            acc[d4].z = p.z + bv.z; acc[d4].w = p.w + bv.w;
        }
        const float4* tp = reinterpret_cast<const float4*>(&tg[row * 512 + h * 64]);
        for (int c4 = 0; c4 < 16; ++c4) {
            const float4 tv = tp[c4];
            const float tc[4] = {tv.x, tv.y, tv.z, tv.w};
            #pragma unroll
            for (int cc = 0; cc < 4; ++cc) {
                const int c = c4 * 4 + cc;
                const float t0 = tc[cc];
                #pragma unroll
                for (int d4 = 0; d4 < 4; ++d4) {
                    const float4 w = *reinterpret_cast<const float4*>(&wva_s[c][20 * h + d4 * 4]);
                    acc[d4].x += t0 * w.x; acc[d4].y += t0 * w.y;
                    acc[d4].z += t0 * w.z; acc[d4].w += t0 * w.w;
                }
            }
        }
        #pragma unroll
        for (int d4 = 0; d4 < 4; ++d4)
            *reinterpret_cast<float4*>(&o_s[r][h * 16 + d4 * 4]) = acc[d4];
    }
    __syncthreads();

    {
        const int e4 = (tid & 31) * 4, rg = tid >> 5;
        const float4 b4 = *reinterpret_cast<const float4*>(&bo[e4]);
        float4 acc[4];
        #pragma unroll
        for (int rr = 0; rr < 4; ++rr) acc[rr] = b4;
        #pragma unroll 4
        for (int k = 0; k < 128; ++k) {
            const float4 w = *reinterpret_cast<const float4*>(&wo_s[k][e4]);
            #pragma unroll
            for (int rr = 0; rr < 4; ++rr) {
                const float ov = o_s[rg * 4 + rr][k];
                acc[rr].x += ov * w.x; acc[rr].y += ov * w.y;
                acc[rr].z += ov * w.z; acc[rr].w += ov * w.w;
            }
        }
        #pragma unroll
        for (int rr = 0; rr < 4; ++rr) {
            const size_t row = (size_t)row0 + rg * 4 + rr;
            const float4 gt = *reinterpret_cast<const float4*>(&gatev[row * NE + e4]);
            float4 o;
            o.x = acc[rr].x * gt.x; o.y = acc[rr].y * gt.y;
            o.z = acc[rr].z * gt.z; o.w = acc[rr].w * gt.w;
            *reinterpret_cast<float4*>(&out[row * NE + e4]) = o;
        }
    }
}

extern "C" void kernel_launch(void* const* d_in, const int* in_sizes, int n_in,
                              void* d_out, int out_size, void* d_ws, size_t ws_size,
                              hipStream_t stream)
{
    const float* pair_emb = (const float*)d_in[0];
    const float* tri_emb  = (const float*)d_in[1];
    const float* mask     = (const float*)d_in[2];
    const float* ln_g = (const float*)d_in[3];
    const float* ln_b = (const float*)d_in[4];
    const float* Wq  = (const float*)d_in[5];  const float* bq  = (const float*)d_in[6];
    const float* Wke = (const float*)d_in[7];  const float* bke = (const float*)d_in[8];
    const float* Wka = (const float*)d_in[9];  const float* bka = (const float*)d_in[10];
    const float* Wv  = (const float*)d_in[11]; const float* bv  = (const float*)d_in[12];
    const float* Wva = (const float*)d_in[13]; const float* bva = (const float*)d_in[14];
    const float* Wo  = (const float*)d_in[15]; const float* bo  = (const float*)d_in[16];
    const float* Wg  = (const float*)d_in[17]; const float* bg  = (const float*)d_in[18];

    float* ws = (float*)d_ws;
    float* qo    = ws;
    float* keo   = qo    + (size_t)NROWS * NE;
    float* veo   = keo   + (size_t)NROWS * NE;
    float* gateo = veo   + (size_t)NROWS * NE;
    float* qwg   = gateo + (size_t)NROWS * NE;
    float* S0g   = qwg   + (size_t)NROWS * 512;
    float* tg    = S0g   + (size_t)NROWS * 512;
    float* preg  = tg    + (size_t)NROWS * 512;

    hipLaunchKernelGGL(tri_k1, dim3(NROWS / 16), dim3(256), 0, stream,
        pair_emb, ln_g, ln_b, Wq, bq, Wke, bke, Wv, bv, Wg, bg,
        qo, keo, veo, gateo);
    hipLaunchKernelGGL(tri_k1b, dim3(NB * NN * 2), dim3(256), 0, stream,
        qo, keo, mask, Wka, bka, S0g, qwg);
    hipLaunchKernelGGL(tri_k2, dim3(NROWS / 8), dim3(256), 0, stream,
        tri_emb, S0g, qwg, veo, tg, preg);
    hipLaunchKernelGGL(tri_k3, dim3(NROWS / 32), dim3(256), 0, stream,
        tg, preg, gateo, Wva, bva, Wo, bo, (float*)d_out);
}

// Round 4
// 121.954 us; speedup vs baseline: 1.2710x; 1.2710x over previous
//
#include <hip/hip_runtime.h>

#define NB 2
#define NN 64
#define NE 128
#define NH 8
#define ND 16
#define NC 64          // E/2
#define NROWS (NB*NN*NN)  // 8192

typedef short short8 __attribute__((ext_vector_type(8)));
typedef float f32x4 __attribute__((ext_vector_type(4)));

__device__ inline unsigned pack_bf2(float a, float b) {
    union { __bf16 h[2]; unsigned u; } v;
    v.h[0] = (__bf16)a; v.h[1] = (__bf16)b;
    return v.u;
}

// ---------------- k1: LayerNorm + 4 projections (q*scale, k_e, v_e, gate) ----------------
__global__ __launch_bounds__(256) void tri_k1(
    const float* __restrict__ pair_emb,
    const float* __restrict__ ln_g, const float* __restrict__ ln_b,
    const float* __restrict__ Wq, const float* __restrict__ bq,
    const float* __restrict__ Wke, const float* __restrict__ bke,
    const float* __restrict__ Wv, const float* __restrict__ bv,
    const float* __restrict__ Wg, const float* __restrict__ bg,
    float* __restrict__ qo, float* __restrict__ keo,
    float* __restrict__ veo, float* __restrict__ gateo)
{
    __shared__ float pe_s[16][NE];
    const int tid = threadIdx.x;
    const int wave = tid >> 6, lane = tid & 63;
    const int row0 = blockIdx.x * 16;

    for (int r = wave * 4; r < wave * 4 + 4; ++r) {
        const int row = row0 + r;
        float2 v = *reinterpret_cast<const float2*>(&pair_emb[(size_t)row * NE + lane * 2]);
        float s = v.x + v.y, s2 = v.x * v.x + v.y * v.y;
        #pragma unroll
        for (int m = 1; m < 64; m <<= 1) { s += __shfl_xor(s, m); s2 += __shfl_xor(s2, m); }
        const float mean = s * (1.0f / NE);
        const float var = fmaxf(s2 * (1.0f / NE) - mean * mean, 0.0f);
        const float inv = rsqrtf(var + 1e-5f);
        pe_s[r][lane * 2]     = (v.x - mean) * inv * ln_g[lane * 2]     + ln_b[lane * 2];
        pe_s[r][lane * 2 + 1] = (v.y - mean) * inv * ln_g[lane * 2 + 1] + ln_b[lane * 2 + 1];
    }
    __syncthreads();

    const int o = tid & 127;
    const int hf = tid >> 7;
    float aq[8] = {0,0,0,0,0,0,0,0}, ak[8] = {0,0,0,0,0,0,0,0};
    float av[8] = {0,0,0,0,0,0,0,0}, ag[8] = {0,0,0,0,0,0,0,0};
    for (int c = 0; c < NE; ++c) {
        const float wq = Wq[c * NE + o];
        const float wk = Wke[c * NE + o];
        const float wv = Wv[c * NE + o];
        const float wg = Wg[c * NE + o];
        #pragma unroll
        for (int r = 0; r < 8; ++r) {
            const float p = pe_s[hf * 8 + r][c];
            aq[r] += p * wq; ak[r] += p * wk; av[r] += p * wv; ag[r] += p * wg;
        }
    }
    #pragma unroll
    for (int r = 0; r < 8; ++r) {
        const size_t row = (size_t)row0 + hf * 8 + r;
        qo[row * NE + o]    = (aq[r] + bq[o]) * 0.25f;
        keo[row * NE + o]   = ak[r] + bke[o];
        veo[row * NE + o]   = av[r] + bv[o];
        gateo[row * NE + o] = 1.0f / (1.0f + __expf(-(ag[r] + bg[o])));
    }
}

// ---------------- k1b: per (b,i,x-half): S0 = q·k_e + q·bka + bias (f32); qw = Wka^T q (bf16) ----
__global__ __launch_bounds__(256) void tri_k1b(
    const float* __restrict__ qv, const float* __restrict__ kev,
    const float* __restrict__ mask,
    const float* __restrict__ Wka, const float* __restrict__ bka,
    float* __restrict__ S0g, unsigned short* __restrict__ qwb)
{
    __shared__ float qt[32][129];
    __shared__ float ket[NN][NE];
    __shared__ float wka_s[NC][NE];
    __shared__ float msk[NN][33];
    __shared__ float bka_s[NE];

    const int tid = threadIdx.x;
    const int blk = blockIdx.x >> 1;
    const int xh  = blockIdx.x & 1;
    const int b = blk >> 6;
    const size_t base = (size_t)blk * NN;
    const int xloc0 = xh * 32;

    #pragma unroll
    for (int k = 0; k < 8; ++k) {
        const int v = tid + k * 256;
        const int r = v >> 5, c4 = (v & 31) * 4;
        *reinterpret_cast<float4*>(&ket[r][c4]) =
            *reinterpret_cast<const float4*>(&kev[(base + r) * NE + c4]);
        *reinterpret_cast<float4*>(&wka_s[r][c4]) =
            *reinterpret_cast<const float4*>(&Wka[(size_t)r * NE + c4]);
    }
    #pragma unroll
    for (int k = 0; k < 4; ++k) {
        const int v = tid + k * 256;
        const int r = v >> 5, c4 = (v & 31) * 4;
        float4 tq = *reinterpret_cast<const float4*>(&qv[(base + xloc0 + r) * NE + c4]);
        qt[r][c4] = tq.x; qt[r][c4+1] = tq.y; qt[r][c4+2] = tq.z; qt[r][c4+3] = tq.w;
    }
    #pragma unroll
    for (int k = 0; k < 8; ++k) {
        const int v = tid + k * 256;
        const int j = v >> 5, xl = v & 31;
        msk[j][xl] = mask[(size_t)b * 4096 + j * 64 + xloc0 + xl];
    }
    if (tid < 32) {
        *reinterpret_cast<float4*>(&bka_s[tid * 4]) =
            *reinterpret_cast<const float4*>(&bka[tid * 4]);
    }
    __syncthreads();

    const int xl = tid & 31, h = tid >> 5;
    const int x = xloc0 + xl;
    float qA[16];
    #pragma unroll
    for (int d = 0; d < 16; ++d) qA[d] = qt[xl][h * 16 + d];
    float qbA = 0.0f;
    #pragma unroll
    for (int d = 0; d < 16; ++d) qbA += qA[d] * bka_s[h * 16 + d];

    for (int j4 = 0; j4 < 16; ++j4) {
        float sA[4];
        #pragma unroll
        for (int jj = 0; jj < 4; ++jj) {
            const int j = j4 * 4 + jj;
            float aA = qbA + 1e-9f * (1.0f - msk[j][xl]);
            const float4* kj = reinterpret_cast<const float4*>(&ket[j][h * 16]);
            #pragma unroll
            for (int d4 = 0; d4 < 4; ++d4) {
                const float4 kv = kj[d4];
                aA += qA[d4*4+0]*kv.x + qA[d4*4+1]*kv.y + qA[d4*4+2]*kv.z + qA[d4*4+3]*kv.w;
            }
            sA[jj] = aA;
        }
        *reinterpret_cast<float4*>(&S0g[(base + x) * 512 + h * 64 + j4 * 4]) =
            make_float4(sA[0], sA[1], sA[2], sA[3]);
    }
    for (int c4 = 0; c4 < 16; ++c4) {
        float sA[4];
        #pragma unroll
        for (int cc = 0; cc < 4; ++cc) {
            const int c = c4 * 4 + cc;
            float aA = 0.0f;
            const float4* wj = reinterpret_cast<const float4*>(&wka_s[c][h * 16]);
            #pragma unroll
            for (int d4 = 0; d4 < 4; ++d4) {
                const float4 wv = wj[d4];
                aA += qA[d4*4+0]*wv.x + qA[d4*4+1]*wv.y + qA[d4*4+2]*wv.z + qA[d4*4+3]*wv.w;
            }
            sA[cc] = aA;
        }
        unsigned u0 = pack_bf2(sA[0], sA[1]);
        unsigned u1 = pack_bf2(sA[2], sA[3]);
        *reinterpret_cast<uint2*>(&qwb[(base + x) * 512 + h * 64 + c4 * 4]) = make_uint2(u0, u1);
    }
}

// ---------------- k2: MFMA, wave-private x-tiles, no main-loop barriers ----------------
// block = 256 thr (4 waves), grid = 512 = (b,i) x quarter. Each wave: 4 x-tiles.
// LDS: triA[4][64][64] bf16 swz + triT[4][64][64] bf16 swz + vevT[128][64] bf16 swz = 80 KB.
__global__ __launch_bounds__(256, 2) void tri_k2(
    const float* __restrict__ tri, const float* __restrict__ S0g,
    const unsigned short* __restrict__ qwb, const float* __restrict__ vev,
    float* __restrict__ tg, float* __restrict__ preg)
{
    __shared__ unsigned short triA[4][4096];
    __shared__ unsigned short triT[4][4096];
    __shared__ unsigned short vevT[8192];

    const int tid = threadIdx.x;
    const int w = tid >> 6, l = tid & 63;
    const int g = l >> 4, lr = l & 15;
    const int bid = blockIdx.x;
    const int bi = bid >> 2, quarter = bid & 3;
    const size_t base_bi = (size_t)bi * NN;
    const int x0 = quarter * 16 + w * 4;

    // prefetch first tile (before barrier; independent)
    float4 pf[16];
    {
        const float4* tp = reinterpret_cast<const float4*>(tri) + (base_bi + x0) * 1024 + l * 16;
        #pragma unroll
        for (int k = 0; k < 16; ++k) pf[k] = tp[k];
    }

    // stage vevT bf16 transposed+swizzled: thread: e = tid>>1, j-half = (tid&1)*32
    {
        const int e = tid >> 1, j0 = (tid & 1) * 32;
        const float* vp = vev + (base_bi + j0) * NE + e;
        #pragma unroll
        for (int q = 0; q < 8; ++q) {
            float f0 = vp[(q*4+0)*NE], f1 = vp[(q*4+1)*NE];
            float f2 = vp[(q*4+2)*NE], f3 = vp[(q*4+3)*NE];
            unsigned u0 = pack_bf2(f0, f1), u1 = pack_bf2(f2, f3);
            const int idx = e * 64 + ((j0 + q * 4) ^ ((e & 7) << 3));
            *reinterpret_cast<unsigned*>(&vevT[idx])     = u0;
            *reinterpret_cast<unsigned*>(&vevT[idx + 2]) = u1;
        }
    }
    __syncthreads();

    unsigned short* tA = triA[w];
    unsigned short* tT = triT[w];

    for (int it = 0; it < 4; ++it) {
        const int x = x0 + it;
        const size_t bix = base_bi + x;

        // convert current tile (lane = row j = l, c = 0..63)
        unsigned pk[32];
        #pragma unroll
        for (int p = 0; p < 16; ++p) {
            pk[2*p]   = pack_bf2(pf[p].x, pf[p].y);
            pk[2*p+1] = pack_bf2(pf[p].z, pf[p].w);
        }
        // issue next-tile prefetch (hides HBM latency under this tile's compute)
        if (it < 3) {
            const float4* tp = reinterpret_cast<const float4*>(tri) + (bix + 1) * 1024 + l * 16;
            #pragma unroll
            for (int k = 0; k < 16; ++k) pf[k] = tp[k];
        }
        // current-tile operand loads (L2): qw bf16 B-frags + S0 f32
        short8 qwf0 = *reinterpret_cast<const short8*>(qwb + bix * 512 + lr * 64 + g * 8);
        short8 qwf1 = *reinterpret_cast<const short8*>(qwb + bix * 512 + lr * 64 + 32 + g * 8);
        float4 s0[4];
        {
            const float4* s0p = reinterpret_cast<const float4*>(S0g + bix * 512 + lr * 64);
            #pragma unroll
            for (int jt = 0; jt < 4; ++jt) s0[jt] = s0p[jt * 4 + g];
        }

        // write triA (row-major swizzled): 8 x b128
        #pragma unroll
        for (int k = 0; k < 8; ++k) {
            const int idx = l * 64 + ((8 * k) ^ ((l & 7) << 3));
            *reinterpret_cast<uint4*>(&tA[idx]) =
                make_uint4(pk[4*k], pk[4*k+1], pk[4*k+2], pk[4*k+3]);
        }
        // write triT (transposed swizzled): 64 x b16, 2-way banks
        #pragma unroll
        for (int c = 0; c < 64; ++c) {
            const unsigned short val = (unsigned short)(pk[c >> 1] >> ((c & 1) * 16));
            tT[c * 64 + (l ^ ((c & 7) << 3))] = val;
        }

        // ---- scores: S[j][h] = tri·qw^T + S0 ----
        f32x4 sc[4];
        #pragma unroll
        for (int jt = 0; jt < 4; ++jt) {
            const int row = jt * 16 + lr;
            short8 a0 = *reinterpret_cast<const short8*>(&tA[row * 64 + ((g * 8) ^ ((row & 7) << 3))]);
            short8 a1 = *reinterpret_cast<const short8*>(&tA[row * 64 + ((32 + g * 8) ^ ((row & 7) << 3))]);
            f32x4 z = {0.f, 0.f, 0.f, 0.f};
            z = __builtin_amdgcn_mfma_f32_16x16x32_bf16(a0, qwf0, z, 0, 0, 0);
            z = __builtin_amdgcn_mfma_f32_16x16x32_bf16(a1, qwf1, z, 0, 0, 0);
            z[0] += s0[jt].x; z[1] += s0[jt].y; z[2] += s0[jt].z; z[3] += s0[jt].w;
            sc[jt] = z;
        }

        // ---- softmax over j (16 vals/lane + lanes l^16, l^32 share h=lr) ----
        float m = sc[0][0];
        #pragma unroll
        for (int jt = 0; jt < 4; ++jt)
            #pragma unroll
            for (int r = 0; r < 4; ++r) m = fmaxf(m, sc[jt][r]);
        m = fmaxf(m, __shfl_xor(m, 16));
        m = fmaxf(m, __shfl_xor(m, 32));
        float sum = 0.0f;
        #pragma unroll
        for (int jt = 0; jt < 4; ++jt)
            #pragma unroll
            for (int r = 0; r < 4; ++r) { float e = __expf(sc[jt][r] - m); sc[jt][r] = e; sum += e; }
        sum += __shfl_xor(sum, 16);
        sum += __shfl_xor(sum, 32);
        const float inv = 1.0f / sum;

        // ---- attn -> bf16 into triA rows 0..15 (dead after scores) ----
        #pragma unroll
        for (int jt = 0; jt < 4; ++jt) {
            unsigned u0 = pack_bf2(sc[jt][0] * inv, sc[jt][1] * inv);
            unsigned u1 = pack_bf2(sc[jt][2] * inv, sc[jt][3] * inv);
            const int j0 = jt * 16 + g * 4;
            const int idx = lr * 64 + (j0 ^ ((lr & 7) << 3));
            *reinterpret_cast<uint2*>(&tA[idx]) = make_uint2(u0, u1);
        }

        // ---- t[h][c] = attn · tri  (A = attn rows h, B = triT) ----
        short8 at0 = *reinterpret_cast<const short8*>(&tA[lr * 64 + ((g * 8) ^ ((lr & 7) << 3))]);
        short8 at1 = *reinterpret_cast<const short8*>(&tA[lr * 64 + ((32 + g * 8) ^ ((lr & 7) << 3))]);
        #pragma unroll
        for (int ct = 0; ct < 4; ++ct) {
            const int row = ct * 16 + lr;
            short8 b0 = *reinterpret_cast<const short8*>(&tT[row * 64 + ((g * 8) ^ ((row & 7) << 3))]);
            short8 b1 = *reinterpret_cast<const short8*>(&tT[row * 64 + ((32 + g * 8) ^ ((row & 7) << 3))]);
            f32x4 z = {0.f, 0.f, 0.f, 0.f};
            z = __builtin_amdgcn_mfma_f32_16x16x32_bf16(at0, b0, z, 0, 0, 0);
            z = __builtin_amdgcn_mfma_f32_16x16x32_bf16(at1, b1, z, 0, 0, 0);
            if (l < 32) {
                #pragma unroll
                for (int r = 0; r < 4; ++r)
                    tg[bix * 512 + (g * 4 + r) * 64 + ct * 16 + lr] = z[r];
            }
        }

        // ---- pre[e] = attn[h] · v_e (broadcast-A, B from vevT) ----
        #pragma unroll
        for (int h = 0; h < 8; ++h) {
            short8 a0 = *reinterpret_cast<const short8*>(&tA[h * 64 + ((g * 8) ^ ((h & 7) << 3))]);
            short8 a1 = *reinterpret_cast<const short8*>(&tA[h * 64 + ((32 + g * 8) ^ ((h & 7) << 3))]);
            const int e = h * 16 + lr;
            short8 b0 = *reinterpret_cast<const short8*>(&vevT[e * 64 + ((g * 8) ^ ((e & 7) << 3))]);
            short8 b1 = *reinterpret_cast<const short8*>(&vevT[e * 64 + ((32 + g * 8) ^ ((e & 7) << 3))]);
            f32x4 z = {0.f, 0.f, 0.f, 0.f};
            z = __builtin_amdgcn_mfma_f32_16x16x32_bf16(a0, b0, z, 0, 0, 0);
            z = __builtin_amdgcn_mfma_f32_16x16x32_bf16(a1, b1, z, 0, 0, 0);
            if (l < 16) preg[bix * NE + h * 16 + lr] = z[0];
        }
    }
}

// ---------------- k3: out = ((pre + bva + t@Wva) @ Wo + bo) * gate ----------------
__global__ __launch_bounds__(256) void tri_k3(
    const float* __restrict__ tg, const float* __restrict__ preg,
    const float* __restrict__ gatev,
    const float* __restrict__ Wva, const float* __restrict__ bva,
    const float* __restrict__ Wo, const float* __restrict__ bo,
    float* __restrict__ out)
{
    __shared__ float wva_s[64][160];
    __shared__ float wo_s[128][128];
    __shared__ float o_s[32][132];

    const int tid = threadIdx.x;
    const int row0 = blockIdx.x * 32;

    #pragma unroll
    for (int k = 0; k < 8; ++k) {
        const int v = tid + k * 256;
        const int c = v >> 5, e4 = (v & 31) * 4;
        const int col = e4 + ((e4 >> 4) << 2);
        *reinterpret_cast<float4*>(&wva_s[c][col]) =
            *reinterpret_cast<const float4*>(&Wva[(size_t)c * NE + e4]);
    }
    #pragma unroll
    for (int k = 0; k < 16; ++k) {
        const int v = tid + k * 256;
        const int kk = v >> 5, e4 = (v & 31) * 4;
        *reinterpret_cast<float4*>(&wo_s[kk][e4]) =
            *reinterpret_cast<const float4*>(&Wo[(size_t)kk * NE + e4]);
    }
    __syncthreads();

    {
        const int r = tid >> 3, h = tid & 7;
        const size_t row = (size_t)row0 + r;
        float4 acc[4];
        #pragma unroll
        for (int d4 = 0; d4 < 4; ++d4) {
            const float4 p  = *reinterpret_cast<const float4*>(&preg[row * NE + h * 16 + d4 * 4]);
            const float4 bv = *reinterpret_cast<const float4*>(&bva[h * 16 + d4 * 4]);
            acc[d4].x = p.x + bv.x; acc[d4].y = p.y + bv.y;
            acc[d4].z = p.z + bv.z; acc[d4].w = p.w + bv.w;
        }
        const float4* tp = reinterpret_cast<const float4*>(&tg[row * 512 + h * 64]);
        for (int c4 = 0; c4 < 16; ++c4) {
            const float4 tv = tp[c4];
            const float tc[4] = {tv.x, tv.y, tv.z, tv.w};
            #pragma unroll
            for (int cc = 0; cc < 4; ++cc) {
                const int c = c4 * 4 + cc;
                const float t0 = tc[cc];
                #pragma unroll
                for (int d4 = 0; d4 < 4; ++d4) {
                    const float4 wv = *reinterpret_cast<const float4*>(&wva_s[c][20 * h + d4 * 4]);
                    acc[d4].x += t0 * wv.x; acc[d4].y += t0 * wv.y;
                    acc[d4].z += t0 * wv.z; acc[d4].w += t0 * wv.w;
                }
            }
        }
        #pragma unroll
        for (int d4 = 0; d4 < 4; ++d4)
            *reinterpret_cast<float4*>(&o_s[r][h * 16 + d4 * 4]) = acc[d4];
    }
    __syncthreads();

    {
        const int e4 = (tid & 31) * 4, rg = tid >> 5;
        const float4 b4 = *reinterpret_cast<const float4*>(&bo[e4]);
        float4 acc[4];
        #pragma unroll
        for (int rr = 0; rr < 4; ++rr) acc[rr] = b4;
        #pragma unroll 4
        for (int k = 0; k < 128; ++k) {
            const float4 wv = *reinterpret_cast<const float4*>(&wo_s[k][e4]);
            #pragma unroll
            for (int rr = 0; rr < 4; ++rr) {
                const float ov = o_s[rg * 4 + rr][k];
                acc[rr].x += ov * wv.x; acc[rr].y += ov * wv.y;
                acc[rr].z += ov * wv.z; acc[rr].w += ov * wv.w;
            }
        }
        #pragma unroll
        for (int rr = 0; rr < 4; ++rr) {
            const size_t row = (size_t)row0 + rg * 4 + rr;
            const float4 gt = *reinterpret_cast<const float4*>(&gatev[row * NE + e4]);
            float4 o;
            o.x = acc[rr].x * gt.x; o.y = acc[rr].y * gt.y;
            o.z = acc[rr].z * gt.z; o.w = acc[rr].w * gt.w;
            *reinterpret_cast<float4*>(&out[row * NE + e4]) = o;
        }
    }
}

extern "C" void kernel_launch(void* const* d_in, const int* in_sizes, int n_in,
                              void* d_out, int out_size, void* d_ws, size_t ws_size,
                              hipStream_t stream)
{
    const float* pair_emb = (const float*)d_in[0];
    const float* tri_emb  = (const float*)d_in[1];
    const float* mask     = (const float*)d_in[2];
    const float* ln_g = (const float*)d_in[3];
    const float* ln_b = (const float*)d_in[4];
    const float* Wq  = (const float*)d_in[5];  const float* bq  = (const float*)d_in[6];
    const float* Wke = (const float*)d_in[7];  const float* bke = (const float*)d_in[8];
    const float* Wka = (const float*)d_in[9];  const float* bka = (const float*)d_in[10];
    const float* Wv  = (const float*)d_in[11]; const float* bv  = (const float*)d_in[12];
    const float* Wva = (const float*)d_in[13]; const float* bva = (const float*)d_in[14];
    const float* Wo  = (const float*)d_in[15]; const float* bo  = (const float*)d_in[16];
    const float* Wg  = (const float*)d_in[17]; const float* bg  = (const float*)d_in[18];

    float* ws = (float*)d_ws;
    float* qo    = ws;                               // 1M floats
    float* keo   = qo    + (size_t)NROWS * NE;       // 1M
    float* veo   = keo   + (size_t)NROWS * NE;       // 1M
    float* gateo = veo   + (size_t)NROWS * NE;       // 1M
    float* S0g   = gateo + (size_t)NROWS * NE;       // 4M
    float* tg    = S0g   + (size_t)NROWS * 512;      // 4M
    float* preg  = tg    + (size_t)NROWS * 512;      // 1M
    unsigned short* qwb = (unsigned short*)(preg + (size_t)NROWS * NE);  // 4M shorts

    hipLaunchKernelGGL(tri_k1, dim3(NROWS / 16), dim3(256), 0, stream,
        pair_emb, ln_g, ln_b, Wq, bq, Wke, bke, Wv, bv, Wg, bg,
        qo, keo, veo, gateo);
    hipLaunchKernelGGL(tri_k1b, dim3(NB * NN * 2), dim3(256), 0, stream,
        qo, keo, mask, Wka, bka, S0g, qwb);
    hipLaunchKernelGGL(tri_k2, dim3(NROWS / 16), dim3(256), 0, stream,
        tri_emb, S0g, qwb, veo, tg, preg);
    hipLaunchKernelGGL(tri_k3, dim3(NROWS / 32), dim3(256), 0, stream,
        tg, preg, gateo, Wva, bva, Wo, bo, (float*)d_out);
}